// Round 2
// baseline (13970.221 us; speedup 1.0000x reference)
//
#include <hip/hip_runtime.h>
#include <math.h>

#define NB   64
#define SS   96
#define EE   300
#define DD   512
#define HH   256
#define SELD 128
#define CK   1280   // 5*H
#define MLPD 1024
#define NCLS 3
#define RB   97     // state rows per batch: 96 initial + 1 spare (freed-row recycling)

// ---------------- transpose kernels: W[e][k] -> W4[e4][k] (float4 of 4 consecutive e) -------------
__global__ void k_trans_comp(const float* __restrict__ Wc, float* __restrict__ Wc4) {
    int e4 = blockIdx.x;            // 0..127
    for (int i = 0; i < 5; i++) {
        int k = threadIdx.x + 256 * i;
        float4 v;
        v.x = Wc[(4 * e4 + 0) * CK + k];
        v.y = Wc[(4 * e4 + 1) * CK + k];
        v.z = Wc[(4 * e4 + 2) * CK + k];
        v.w = Wc[(4 * e4 + 3) * CK + k];
        ((float4*)Wc4)[e4 * CK + k] = v;
    }
}

__global__ void k_trans_sel(const float* __restrict__ Ws, float* __restrict__ Ws4) {
    int e4 = blockIdx.x;            // 0..127
    int k = threadIdx.x;            // 0..127
    float4 v;
    v.x = Ws[(4 * e4 + 0) * SELD + k];
    v.y = Ws[(4 * e4 + 1) * SELD + k];
    v.z = Ws[(4 * e4 + 2) * SELD + k];
    v.w = Ws[(4 * e4 + 3) * SELD + k];
    ((float4*)Ws4)[e4 * SELD + k] = v;
}

// ---------------- encode: states[b][s][:] = emb[sent[b][s]] @ W_enc + b_enc ----------------------
__global__ __launch_bounds__(512) void k_encode(const int* __restrict__ sent,
                                                const float* __restrict__ emb,
                                                const float* __restrict__ Wenc,
                                                const float* __restrict__ benc,
                                                float* __restrict__ state) {
    int b = blockIdx.x / 3, tile = blockIdx.x % 3, s0 = tile * 32;
    __shared__ int tok[32];
    __shared__ __align__(16) float elds[32 * 300];
    int tid = threadIdx.x;
    if (tid < 32) tok[tid] = sent[b * SS + s0 + tid];
    __syncthreads();
    for (int i = tid; i < 32 * 300; i += 512) {
        int s = i / 300, e = i - s * 300;
        elds[i] = emb[(long)tok[s] * EE + e];
    }
    __syncthreads();
    int d = tid;
    float bv = benc[d];
    float acc[32];
#pragma unroll
    for (int s = 0; s < 32; s++) acc[s] = bv;
    for (int e4 = 0; e4 < 75; e4++) {
        float w0 = Wenc[(4 * e4 + 0) * DD + d];
        float w1 = Wenc[(4 * e4 + 1) * DD + d];
        float w2 = Wenc[(4 * e4 + 2) * DD + d];
        float w3 = Wenc[(4 * e4 + 3) * DD + d];
#pragma unroll
        for (int s = 0; s < 32; s++) {
            float4 x = *(const float4*)&elds[s * 300 + 4 * e4];
            acc[s] += x.x * w0 + x.y * w1 + x.z * w2 + x.w * w3;
        }
    }
    for (int s = 0; s < 32; s++)
        state[((size_t)b * RB + s0 + s) * DD + d] = acc[s];
}

// ---------------- initial logits for all 95 pairs per batch -------------------------------------
__global__ __launch_bounds__(128) void k_logits0(const float* __restrict__ state,
                                                 const float* __restrict__ Ws4,
                                                 const float* __restrict__ bs1,
                                                 const float* __restrict__ Ws2,
                                                 const float* __restrict__ bs2,
                                                 float* __restrict__ log0) {
    int b = blockIdx.x / 5, tile = blockIdx.x % 5, p0 = tile * 19;
    __shared__ __align__(16) float hl[20 * 256];     // h rows p0..p0+19
    __shared__ float part[2][19];
    int tid = threadIdx.x;
    for (int i = tid; i < 20 * 256; i += 128) {
        int r = i >> 8, c = i & 255;
        hl[i] = state[((size_t)b * RB + p0 + r) * DD + HH + c];
    }
    __syncthreads();
    int k = tid;
    float acc[19];
#pragma unroll
    for (int p = 0; p < 19; p++) acc[p] = 0.f;
    const float4* W4 = (const float4*)Ws4;
    const float4* h4 = (const float4*)hl;
    for (int e4 = 0; e4 < 128; e4++) {
        float4 w = W4[e4 * SELD + k];
#pragma unroll
        for (int p = 0; p < 19; p++) {
            float4 x = h4[p * 64 + e4];
            acc[p] += x.x * w.x + x.y * w.y + x.z * w.z + x.w * w.w;
        }
    }
    float b1 = bs1[k], w2 = Ws2[k];
    int wid = tid >> 6, lane = tid & 63;
#pragma unroll
    for (int p = 0; p < 19; p++) {
        float y = tanhf(acc[p] + b1) * w2;
        for (int off = 32; off >= 1; off >>= 1) y += __shfl_down(y, off);
        if (lane == 0) part[wid][p] = y;
    }
    __syncthreads();
    if (tid < 19) log0[b * 95 + p0 + tid] = part[0][tid] + part[1][tid] + bs2[0];
}

// ---------------- group barrier among the 4 blocks of a batch -----------------------------------
__device__ __forceinline__ void groupbar(int* cnt, int target) {
    __hip_atomic_fetch_add(cnt, 1, __ATOMIC_ACQ_REL, __HIP_MEMORY_SCOPE_AGENT);
    while (__hip_atomic_load(cnt, __ATOMIC_ACQUIRE, __HIP_MEMORY_SCOPE_AGENT) < target) {
        __builtin_amdgcn_s_sleep(2);
    }
}

// ---------------- the sequential scan: 4 blocks per batch ---------------------------------------
// block q of group grp: owns output-column slice {g*256 + q*64 + u : g in [0,5), u in [0,64)} of
// W_comp (column split, all 5 gates for a 64-slice of H -> no cross-block gate exchange), and
// K-slice [q*128,(q+1)*128) of W_sel1 (partials exchanged via wpart).
__global__ __launch_bounds__(1024) void k_scan4(const float* __restrict__ Wc4,
                                                const float* __restrict__ bcomp,
                                                const float* __restrict__ Ws4,
                                                const float* __restrict__ bs1,
                                                const float* __restrict__ Ws2,
                                                const float* __restrict__ bs2,
                                                const float* __restrict__ log0,
                                                float* __restrict__ state,
                                                float* __restrict__ hroot,
                                                float* __restrict__ wpart,
                                                int* __restrict__ cnt,
                                                int force) {
    int grp = blockIdx.x & 63;      // batch; blocks {grp, grp+64, grp+128, grp+192} form the group
    int q   = blockIdx.x >> 6;      // 0..3
    int tid = threadIdx.x;

    __shared__ int act[SS];
    __shared__ float logit[SS - 1];
    __shared__ __align__(16) float xcomp[DD];        // [h_l | h_r]
    __shared__ __align__(16) float lc[64], rc[64];   // own c-slices of left/right
    __shared__ float p1[4][4][64];                   // [ks][g][u] K-quarter partials, gates 0..3
    __shared__ float p2[16][64];                     // [ks16][u] partials for gate 4 (gc)
    __shared__ __align__(16) float xsel[2][SELD];    // own K-slice of each refreshed pair's input
    __shared__ float sred[2][4][SELD];
    __shared__ float red2[2][2];
    __shared__ float amax_v[2];
    __shared__ int amax_i[2];
    __shared__ int s_idx;
    __shared__ float pad_lds[17000];                 // force 1 block/CU (LDS > 80 KB)
    if (force) pad_lds[tid] = 0.f;

    float* st = state + (size_t)grp * RB * DD;
    int* mycnt = cnt + grp;

    if (tid < SS) act[tid] = tid;
    if (tid < SS - 1) logit[tid] = log0[grp * (SS - 1) + tid];
    __syncthreads();

    int freeRow = SS;   // row 96 is the spare; thereafter reuse the row freed last step
    for (int t = 0; t < SS - 1; t++) {
        int n = SS - t;
        // ---- (1) argmax over logit[0..n-2], numpy first-max semantics (identical in all blocks)
        if (tid < 128) {
            int p = tid;
            float v = (p < n - 1) ? logit[p] : -3.0e38f;
            int i = p;
#pragma unroll
            for (int off = 1; off < 64; off <<= 1) {
                float ov = __shfl_xor(v, off);
                int oi = __shfl_xor(i, off);
                if (ov > v || (ov == v && oi < i)) { v = ov; i = oi; }
            }
            if ((tid & 63) == 0) { amax_v[tid >> 6] = v; amax_i[tid >> 6] = i; }
        }
        __syncthreads();
        if (tid == 0) {
            float v0 = amax_v[0], v1 = amax_v[1];
            int i0 = amax_i[0], i1 = amax_i[1];
            s_idx = (v1 > v0 || (v1 == v0 && i1 < i0)) ? i1 : i0;
        }
        __syncthreads();
        int idx = s_idx;
        int l = act[idx], r = act[idx + 1];
        int lm1 = (idx >= 1) ? act[idx - 1] : 0;
        int r2  = (idx + 2 <= n - 1) ? act[idx + 2] : 0;
        bool v0ok = (idx >= 1);
        bool v1ok = (idx <= n - 3);
        int nl = freeRow;                            // compose target: fresh row, nobody reads it
        // save shift sources before any bookkeeping writes
        int pA = -1, tA = 0, pL = -1; float tL = 0.f;
        if (tid >= idx + 1 && tid <= n - 2) { pA = tid; tA = act[tid + 1]; }
        if (tid >= idx + 1 && tid <= n - 3) { pL = tid; tL = logit[tid + 1]; }

        // ---- (2) stage [h_l | h_r] (full) + own c-slices (vectorized) ----
        if (tid < 64)        ((float4*)xcomp)[tid]      = ((const float4*)(st + (size_t)l * DD + HH))[tid];
        else if (tid < 128)  ((float4*)xcomp)[tid]      = ((const float4*)(st + (size_t)r * DD + HH))[tid - 64];
        else if (tid < 144)  ((float4*)lc)[tid - 128]   = ((const float4*)(st + (size_t)l * DD + q * 64))[tid - 128];
        else if (tid < 160)  ((float4*)rc)[tid - 144]   = ((const float4*)(st + (size_t)r * DD + q * 64))[tid - 144];
        __syncthreads();

        // ---- (3) compose matvec: own 320 columns ----
        {   // gates 0..3 (i,fl,fr,o): (u, g, ks) = 64 x 4 x 4, K-quarter each
            int u = tid & 63, g = (tid >> 6) & 3, ks = tid >> 8;
            int c = g * 256 + q * 64 + u;
            const float4* W4 = (const float4*)Wc4;
            const float4* x4 = (const float4*)xcomp;
            float acc = 0.f;
#pragma unroll 8
            for (int e4 = ks * 32; e4 < ks * 32 + 32; e4++) {
                float4 xv = x4[e4];
                float4 wv = W4[(size_t)e4 * CK + c];
                acc += xv.x * wv.x + xv.y * wv.y + xv.z * wv.z + xv.w * wv.w;
            }
            p1[ks][g][u] = acc;
        }
        {   // gate 4 (gc): (u, ks16) = 64 x 16, K/16 each
            int u = tid & 63, k16 = tid >> 6;
            int c = 1024 + q * 64 + u;
            const float4* W4 = (const float4*)Wc4;
            const float4* x4 = (const float4*)xcomp;
            float acc = 0.f;
#pragma unroll
            for (int e4 = k16 * 8; e4 < k16 * 8 + 8; e4++) {
                float4 xv = x4[e4];
                float4 wv = W4[(size_t)e4 * CK + c];
                acc += xv.x * wv.x + xv.y * wv.y + xv.z * wv.z + xv.w * wv.w;
            }
            p2[k16][u] = acc;
        }
        __syncthreads();
        // ---- (4) gates + compose for own u-slice; write into fresh row nl ----
        if (tid < 64) {
            int u = tid;
            float ai  = p1[0][0][u] + p1[1][0][u] + p1[2][0][u] + p1[3][0][u] + bcomp[        q * 64 + u];
            float afl = p1[0][1][u] + p1[1][1][u] + p1[2][1][u] + p1[3][1][u] + bcomp[ 256 +  q * 64 + u];
            float afr = p1[0][2][u] + p1[1][2][u] + p1[2][2][u] + p1[3][2][u] + bcomp[ 512 +  q * 64 + u];
            float ao  = p1[0][3][u] + p1[1][3][u] + p1[2][3][u] + p1[3][3][u] + bcomp[ 768 +  q * 64 + u];
            float agc = 0.f;
#pragma unroll
            for (int ks = 0; ks < 16; ks++) agc += p2[ks][u];
            agc += bcomp[1024 + q * 64 + u];
            float si  = 1.f / (1.f + expf(-ai));
            float sfl = 1.f / (1.f + expf(-afl));
            float sfr = 1.f / (1.f + expf(-afr));
            float so  = 1.f / (1.f + expf(-ao));
            float cv = sfl * lc[u] + sfr * rc[u] + si * tanhf(agc);
            float hv = so * tanhf(cv);
            st[(size_t)nl * DD + q * 64 + u] = cv;
            st[(size_t)nl * DD + HH + q * 64 + u] = hv;
        }
        __threadfence();
        __syncthreads();
        if (tid == 0) groupbar(mycnt, 8 * t + 4);    // barrier A: comp row visible
        __syncthreads();

        // ---- (5) stage own K-slice of the 2 refreshed pairs' inputs ----
        // pair0: x = [h_lm1 | comp_h]; pair1: x = [comp_h | h_r2]
        if (tid < 64) {
            int pr = tid >> 5, j4 = tid & 31;        // 32 float4 = 128 floats per slice
            int gpos4 = q * 32 + j4;                 // float4 pos in the 512-float x
            bool valid = (pr == 0) ? v0ok : v1ok;
            int row = (pr == 0) ? ((gpos4 < 64) ? lm1 : nl)
                                : ((gpos4 < 64) ? nl : r2);
            int off4 = (HH >> 2) + (gpos4 & 63);
            float4 v = make_float4(0.f, 0.f, 0.f, 0.f);
            if (valid) v = ((const float4*)(st + (size_t)row * DD))[off4];
            ((float4*)xsel[pr])[j4] = v;
        }
        __syncthreads();
        // ---- (6) selection partials over own K-slice of W_sel1 ----
        {
            int pr = tid >> 9, sub = (tid >> 7) & 3, k = tid & 127;
            const float4* W4 = (const float4*)Ws4;
            const float4* x4 = (const float4*)xsel[pr];
            float acc = 0.f;
#pragma unroll
            for (int le = sub * 8; le < sub * 8 + 8; le++) {
                int e4 = q * 32 + le;
                float4 xv = x4[le];
                float4 wv = W4[(size_t)e4 * SELD + k];
                acc += xv.x * wv.x + xv.y * wv.y + xv.z * wv.z + xv.w * wv.w;
            }
            sred[pr][sub][k] = acc;
        }
        __syncthreads();
        if (tid < 256) {
            int pr = tid >> 7, k = tid & 127;
            wpart[((size_t)grp * 4 + q) * 2 * SELD + pr * SELD + k] =
                sred[pr][0][k] + sred[pr][1][k] + sred[pr][2][k] + sred[pr][3][k];
        }
        __threadfence();
        __syncthreads();
        if (tid == 0) groupbar(mycnt, 8 * t + 8);    // barrier B: partials visible
        __syncthreads();
        // ---- (7) finalize both logits (redundantly, deterministic order q=0..3) ----
        {
            float y = 0.f;
            if (tid < 256) {
                int pr = tid >> 7, k = tid & 127;
                size_t base = (size_t)grp * 1024 + pr * SELD + k;
                float s = wpart[base] + wpart[base + 256] + wpart[base + 512] + wpart[base + 768] + bs1[k];
                y = tanhf(s) * Ws2[k];
            }
#pragma unroll
            for (int off = 32; off >= 1; off >>= 1) y += __shfl_down(y, off);
            if (tid < 256 && (tid & 63) == 0) red2[tid >> 7][(tid >> 6) & 1] = y;
        }
        __syncthreads();
        // ---- (8) bookkeeping (identical in all blocks) ----
        if (pA >= 0) act[pA] = tA;
        if (pL >= 0) logit[pL] = tL;
        if (tid == 0) {
            act[idx] = nl;
            if (v0ok) logit[idx - 1] = red2[0][0] + red2[0][1] + bs2[0];
            if (v1ok) logit[idx]     = red2[1][0] + red2[1][1] + bs2[0];
        }
        __syncthreads();
        freeRow = l;                                 // row l freed this step -> reuse next step
    }
    if (q == 0 && tid < HH) hroot[grp * HH + tid] = st[(size_t)act[0] * DD + HH + tid];
}

// ---------------- final MLP head ----------------------------------------------------------------
__global__ __launch_bounds__(256) void k_mlp(const float* __restrict__ hroot,
                                             const float* __restrict__ Wm1, const float* __restrict__ bm1,
                                             const float* __restrict__ Wm2, const float* __restrict__ bm2,
                                             const float* __restrict__ Wout, const float* __restrict__ bout,
                                             float* __restrict__ out) {
    int b = blockIdx.x, tid = threadIdx.x;
    __shared__ float x0[HH];
    __shared__ float x1[MLPD];
    __shared__ float x2[MLPD];
    __shared__ float red3[3][256];
    if (tid < HH) x0[tid] = hroot[b * HH + tid];
    __syncthreads();
    {
        float a0 = bm1[tid], a1 = bm1[256 + tid], a2 = bm1[512 + tid], a3 = bm1[768 + tid];
        for (int e = 0; e < HH; e++) {
            float x = x0[e];
            a0 += x * Wm1[e * MLPD + tid];
            a1 += x * Wm1[e * MLPD + 256 + tid];
            a2 += x * Wm1[e * MLPD + 512 + tid];
            a3 += x * Wm1[e * MLPD + 768 + tid];
        }
        x1[tid] = fmaxf(a0, 0.f); x1[256 + tid] = fmaxf(a1, 0.f);
        x1[512 + tid] = fmaxf(a2, 0.f); x1[768 + tid] = fmaxf(a3, 0.f);
    }
    __syncthreads();
    {
        float a0 = bm2[tid], a1 = bm2[256 + tid], a2 = bm2[512 + tid], a3 = bm2[768 + tid];
        for (int e = 0; e < MLPD; e++) {
            float x = x1[e];
            a0 += x * Wm2[e * MLPD + tid];
            a1 += x * Wm2[e * MLPD + 256 + tid];
            a2 += x * Wm2[e * MLPD + 512 + tid];
            a3 += x * Wm2[e * MLPD + 768 + tid];
        }
        x2[tid] = fmaxf(a0, 0.f); x2[256 + tid] = fmaxf(a1, 0.f);
        x2[512 + tid] = fmaxf(a2, 0.f); x2[768 + tid] = fmaxf(a3, 0.f);
    }
    __syncthreads();
    {
        float p0 = 0.f, p1 = 0.f, p2 = 0.f;
        for (int e = tid; e < MLPD; e += 256) {
            float x = x2[e];
            p0 += x * Wout[e * NCLS + 0];
            p1 += x * Wout[e * NCLS + 1];
            p2 += x * Wout[e * NCLS + 2];
        }
        red3[0][tid] = p0; red3[1][tid] = p1; red3[2][tid] = p2;
        __syncthreads();
        for (int sdd = 128; sdd >= 1; sdd >>= 1) {
            if (tid < sdd) {
                red3[0][tid] += red3[0][tid + sdd];
                red3[1][tid] += red3[1][tid + sdd];
                red3[2][tid] += red3[2][tid + sdd];
            }
            __syncthreads();
        }
        if (tid < NCLS) out[b * NCLS + tid] = red3[tid][0] + bout[tid];
    }
}

extern "C" void kernel_launch(void* const* d_in, const int* in_sizes, int n_in,
                              void* d_out, int out_size, void* d_ws, size_t ws_size,
                              hipStream_t stream) {
    const int*   sent  = (const int*)d_in[0];
    // d_in[1] = transitions: unused by the reference
    const float* emb   = (const float*)d_in[2];
    const float* Wenc  = (const float*)d_in[3];
    const float* benc  = (const float*)d_in[4];
    const float* Wcomp = (const float*)d_in[5];
    const float* bcomp = (const float*)d_in[6];
    const float* Wsel1 = (const float*)d_in[7];
    const float* bs1   = (const float*)d_in[8];
    const float* Ws2   = (const float*)d_in[9];
    const float* bs2   = (const float*)d_in[10];
    const float* Wm1   = (const float*)d_in[11];
    const float* bm1   = (const float*)d_in[12];
    const float* Wm2   = (const float*)d_in[13];
    const float* bm2   = (const float*)d_in[14];
    const float* Wout  = (const float*)d_in[15];
    const float* bout  = (const float*)d_in[16];
    float* out = (float*)d_out;

    float* ws    = (float*)d_ws;
    float* state = ws;                               // 64*97*512 = 3,178,496 f32
    float* Wc4   = ws + 3178496;                     // 655,360 f32
    float* Ws14  = ws + 3178496 + 655360;            // 65,536 f32
    float* log0  = ws + 3899392;                     // 6,080 f32
    float* hroot = ws + 3905472;                     // 16,384 f32
    float* wpart = ws + 3921856;                     // 64*4*2*128 = 65,536 f32
    int*   cnt   = (int*)(ws + 3987392);             // 64 ints

    hipMemsetAsync(cnt, 0, NB * sizeof(int), stream);
    k_trans_comp<<<dim3(128), dim3(256), 0, stream>>>(Wcomp, Wc4);
    k_trans_sel<<<dim3(128), dim3(128), 0, stream>>>(Wsel1, Ws14);
    k_encode<<<dim3(NB * 3), dim3(512), 0, stream>>>(sent, emb, Wenc, benc, state);
    k_logits0<<<dim3(NB * 5), dim3(128), 0, stream>>>(state, Ws14, bs1, Ws2, bs2, log0);
    k_scan4<<<dim3(256), dim3(1024), 0, stream>>>(Wc4, bcomp, Ws14, bs1, Ws2, bs2,
                                                  log0, state, hroot, wpart, cnt, 0);
    k_mlp<<<dim3(NB), dim3(256), 0, stream>>>(hroot, Wm1, bm1, Wm2, bm2, Wout, bout, out);
}

// Round 3
// 2262.427 us; speedup vs baseline: 6.1749x; 6.1749x over previous
//
#include <hip/hip_runtime.h>
#include <math.h>

#define NB   64
#define SS   96
#define EE   300
#define DD   512
#define HH   256
#define SELD 128
#define CK   1280   // 5*H
#define MLPD 1024
#define NCLS 3
#define RB   97     // state rows per batch: 96 initial + 1 spare (freed-row recycling)

// ---------------- transpose kernels: W[e][k] -> W4[e4][k] (float4 of 4 consecutive e) -------------
__global__ void k_trans_comp(const float* __restrict__ Wc, float* __restrict__ Wc4) {
    int e4 = blockIdx.x;            // 0..127
    for (int i = 0; i < 5; i++) {
        int k = threadIdx.x + 256 * i;
        float4 v;
        v.x = Wc[(4 * e4 + 0) * CK + k];
        v.y = Wc[(4 * e4 + 1) * CK + k];
        v.z = Wc[(4 * e4 + 2) * CK + k];
        v.w = Wc[(4 * e4 + 3) * CK + k];
        ((float4*)Wc4)[e4 * CK + k] = v;
    }
}

__global__ void k_trans_sel(const float* __restrict__ Ws, float* __restrict__ Ws4) {
    int e4 = blockIdx.x;            // 0..127
    int k = threadIdx.x;            // 0..127
    float4 v;
    v.x = Ws[(4 * e4 + 0) * SELD + k];
    v.y = Ws[(4 * e4 + 1) * SELD + k];
    v.z = Ws[(4 * e4 + 2) * SELD + k];
    v.w = Ws[(4 * e4 + 3) * SELD + k];
    ((float4*)Ws4)[e4 * SELD + k] = v;
}

// ---------------- init per-batch bookkeeping (parity 0) -----------------------------------------
__global__ void k_init(int* __restrict__ acts, int* __restrict__ freeR) {
    int b = blockIdx.x, tid = threadIdx.x;
    acts[b * SS + tid] = tid;              // parity-0 half
    if (tid == 0) freeR[b] = SS;           // spare row 96
}

// ---------------- encode: states[b][s][:] = emb[sent[b][s]] @ W_enc + b_enc ----------------------
__global__ __launch_bounds__(512) void k_encode(const int* __restrict__ sent,
                                                const float* __restrict__ emb,
                                                const float* __restrict__ Wenc,
                                                const float* __restrict__ benc,
                                                float* __restrict__ state) {
    int b = blockIdx.x / 3, tile = blockIdx.x % 3, s0 = tile * 32;
    __shared__ int tok[32];
    __shared__ __align__(16) float elds[32 * 300];
    int tid = threadIdx.x;
    if (tid < 32) tok[tid] = sent[b * SS + s0 + tid];
    __syncthreads();
    for (int i = tid; i < 32 * 300; i += 512) {
        int s = i / 300, e = i - s * 300;
        elds[i] = emb[(long)tok[s] * EE + e];
    }
    __syncthreads();
    int d = tid;
    float bv = benc[d];
    float acc[32];
#pragma unroll
    for (int s = 0; s < 32; s++) acc[s] = bv;
    for (int e4 = 0; e4 < 75; e4++) {
        float w0 = Wenc[(4 * e4 + 0) * DD + d];
        float w1 = Wenc[(4 * e4 + 1) * DD + d];
        float w2 = Wenc[(4 * e4 + 2) * DD + d];
        float w3 = Wenc[(4 * e4 + 3) * DD + d];
#pragma unroll
        for (int s = 0; s < 32; s++) {
            float4 x = *(const float4*)&elds[s * 300 + 4 * e4];
            acc[s] += x.x * w0 + x.y * w1 + x.z * w2 + x.w * w3;
        }
    }
    for (int s = 0; s < 32; s++)
        state[((size_t)b * RB + s0 + s) * DD + d] = acc[s];
}

// ---------------- initial logits for all 95 pairs per batch (into parity-0 buffer) ---------------
__global__ __launch_bounds__(128) void k_logits0(const float* __restrict__ state,
                                                 const float* __restrict__ Ws4,
                                                 const float* __restrict__ bs1,
                                                 const float* __restrict__ Ws2,
                                                 const float* __restrict__ bs2,
                                                 float* __restrict__ logits) {
    int b = blockIdx.x / 5, tile = blockIdx.x % 5, p0 = tile * 19;
    __shared__ __align__(16) float hl[20 * 256];     // h rows p0..p0+19
    __shared__ float part[2][19];
    int tid = threadIdx.x;
    for (int i = tid; i < 20 * 256; i += 128) {
        int r = i >> 8, c = i & 255;
        hl[i] = state[((size_t)b * RB + p0 + r) * DD + HH + c];
    }
    __syncthreads();
    int k = tid;
    float acc[19];
#pragma unroll
    for (int p = 0; p < 19; p++) acc[p] = 0.f;
    const float4* W4 = (const float4*)Ws4;
    const float4* h4 = (const float4*)hl;
    for (int e4 = 0; e4 < 128; e4++) {
        float4 w = W4[e4 * SELD + k];
#pragma unroll
        for (int p = 0; p < 19; p++) {
            float4 x = h4[p * 64 + e4];
            acc[p] += x.x * w.x + x.y * w.y + x.z * w.z + x.w * w.w;
        }
    }
    float b1 = bs1[k], w2 = Ws2[k];
    int wid = tid >> 6, lane = tid & 63;
#pragma unroll
    for (int p = 0; p < 19; p++) {
        float y = tanhf(acc[p] + b1) * w2;
        for (int off = 32; off >= 1; off >>= 1) y += __shfl_down(y, off);
        if (lane == 0) part[wid][p] = y;
    }
    __syncthreads();
    if (tid < 19) logits[b * SS + p0 + tid] = part[0][tid] + part[1][tid] + bs2[0];
}

// ---------------- per-wave redundant argmax (numpy first-max semantics) --------------------------
__device__ __forceinline__ int argmax95(const float* __restrict__ lg, int n, int lane) {
    float v = (lane < n - 1) ? lg[lane] : -3.0e38f;
    int i = lane;
    float v2 = (lane + 64 < n - 1) ? lg[lane + 64] : -3.0e38f;
    if (v2 > v) { v = v2; i = lane + 64; }
#pragma unroll
    for (int off = 1; off < 64; off <<= 1) {
        float ov = __shfl_xor(v, off);
        int oi = __shfl_xor(i, off);
        if (ov > v || (ov == v && oi < i)) { v = ov; i = oi; }
    }
    return i;
}

// ---------------- step kernel A: compose (all batches, 4 column-slice blocks each) ---------------
__global__ __launch_bounds__(320) void k_stepA(const float* __restrict__ Wc4,
                                               const float* __restrict__ bcomp,
                                               const float* __restrict__ logits,
                                               const int* __restrict__ acts,
                                               const int* __restrict__ freeR,
                                               float* __restrict__ state, int t) {
    int b = blockIdx.x & 63, q = blockIdx.x >> 6;
    int tid = threadIdx.x, lane = tid & 63;
    int n = SS - t, p = t & 1;
    const float* lg = logits + ((size_t)p * NB + b) * SS;
    const int* ac = acts + ((size_t)p * NB + b) * SS;

    int idx = argmax95(lg, n, lane);
    int l = ac[idx], r = ac[idx + 1];
    int nl = freeR[p * NB + b];
    float* st = state + (size_t)b * RB * DD;

    __shared__ __align__(16) float4 x4[128];     // [h_l | h_r]
    __shared__ float lc[64], rc[64];
    __shared__ float pg[5][64];
    if (tid < 64)        x4[tid] = ((const float4*)(st + (size_t)l * DD + HH))[tid];
    else if (tid < 128)  x4[tid - 64 + 64] = ((const float4*)(st + (size_t)r * DD + HH))[tid - 64];
    else if (tid < 192)  lc[tid - 128] = st[(size_t)l * DD + q * 64 + (tid - 128)];
    else if (tid < 256)  rc[tid - 192] = st[(size_t)r * DD + q * 64 + (tid - 192)];
    __syncthreads();

    int u = tid & 63, g = tid >> 6;              // g in 0..4 (5 waves)
    int c = (g < 4) ? (g * 256 + q * 64 + u) : (1024 + q * 64 + u);
    const float4* W4 = (const float4*)Wc4;
    float acc = bcomp[c];
#pragma unroll 8
    for (int e4 = 0; e4 < 128; e4++) {
        float4 xv = x4[e4];
        float4 wv = W4[(size_t)e4 * CK + c];
        acc += xv.x * wv.x + xv.y * wv.y + xv.z * wv.z + xv.w * wv.w;
    }
    pg[g][u] = acc;
    __syncthreads();

    if (tid < 64) {
        float ai = pg[0][u], afl = pg[1][u], afr = pg[2][u], ao = pg[3][u], agc = pg[4][u];
        float si  = 1.f / (1.f + expf(-ai));
        float sfl = 1.f / (1.f + expf(-afl));
        float sfr = 1.f / (1.f + expf(-afr));
        float so  = 1.f / (1.f + expf(-ao));
        float cv = sfl * lc[u] + sfr * rc[u] + si * tanhf(agc);
        float hv = so * tanhf(cv);
        st[(size_t)nl * DD + q * 64 + u] = cv;
        st[(size_t)nl * DD + HH + q * 64 + u] = hv;
    }
}

// ---------------- step kernel B: refresh 2 logits + shift bookkeeping into parity t+1 ------------
__global__ __launch_bounds__(256) void k_stepB(const float* __restrict__ Ws4,
                                               const float* __restrict__ bs1,
                                               const float* __restrict__ Ws2,
                                               const float* __restrict__ bs2,
                                               float* __restrict__ logits,
                                               int* __restrict__ acts,
                                               int* __restrict__ freeR,
                                               const float* __restrict__ state, int t) {
    int b = blockIdx.x & 63, pr = blockIdx.x >> 6;
    int tid = threadIdx.x, lane = tid & 63;
    int n = SS - t, p = t & 1, np = p ^ 1;
    const float* lgo = logits + ((size_t)p * NB + b) * SS;
    const int*  aco  = acts + ((size_t)p * NB + b) * SS;
    float* lgn = logits + ((size_t)np * NB + b) * SS;
    int*   acn = acts + ((size_t)np * NB + b) * SS;

    int idx = argmax95(lgo, n, lane);
    int l = aco[idx];
    int nl = freeR[p * NB + b];
    bool valid = (pr == 0) ? (idx >= 1) : (idx <= n - 3);
    int rowA = (pr == 0) ? ((idx >= 1) ? aco[idx - 1] : 0) : nl;
    int rowB = (pr == 0) ? nl : ((idx <= n - 3) ? aco[idx + 2] : 0);
    const float* st = state + (size_t)b * RB * DD;

    int k = tid & 127, ks = tid >> 7;            // K halves: ks=0 -> rowA h, ks=1 -> rowB h
    float acc = 0.f;
    if (valid) {
        const float4* h4 = (const float4*)(st + (size_t)(ks ? rowB : rowA) * DD + HH);
        const float4* W4 = (const float4*)Ws4;
#pragma unroll 8
        for (int e4 = 0; e4 < 64; e4++) {
            float4 xv = h4[e4];
            float4 wv = W4[(size_t)(ks * 64 + e4) * SELD + k];
            acc += xv.x * wv.x + xv.y * wv.y + xv.z * wv.z + xv.w * wv.w;
        }
    }
    __shared__ float spart[2][SELD];
    __shared__ float red[2];
    spart[ks][k] = acc;
    __syncthreads();
    float y = 0.f;
    if (tid < 128) {
        float s = spart[0][k] + spart[1][k] + bs1[k];
        y = tanhf(s) * Ws2[k];
    }
#pragma unroll
    for (int off = 32; off >= 1; off >>= 1) y += __shfl_down(y, off);
    if (tid < 128 && lane == 0) red[tid >> 6] = y;
    __syncthreads();
    float lv = red[0] + red[1] + bs2[0];

    if (pr == 0) {
        // act_new: length n-1 (positions 0..n-2)
        if (tid <= n - 2) acn[tid] = (tid < idx) ? aco[tid] : ((tid == idx) ? nl : aco[tid + 1]);
        // logits_new: length n-2 (positions 0..n-3); skip idx-1 (pair0) and idx (pair1)
        if (tid <= n - 3 && tid != idx - 1 && tid != idx)
            lgn[tid] = (tid < idx - 1) ? lgo[tid] : lgo[tid + 1];
        if (tid == 0) {
            freeR[np * NB + b] = l;
            if (valid) lgn[idx - 1] = lv;
        }
    } else {
        if (tid == 0 && valid) lgn[idx] = lv;
    }
}

// ---------------- final MLP head ----------------------------------------------------------------
__global__ __launch_bounds__(256) void k_mlp(const float* __restrict__ state,
                                             const int* __restrict__ freeR,
                                             const float* __restrict__ Wm1, const float* __restrict__ bm1,
                                             const float* __restrict__ Wm2, const float* __restrict__ bm2,
                                             const float* __restrict__ Wout, const float* __restrict__ bout,
                                             float* __restrict__ out) {
    int b = blockIdx.x, tid = threadIdx.x;
    __shared__ float x0[HH];
    __shared__ float x1[MLPD];
    __shared__ float x2[MLPD];
    __shared__ float red3[3][256];
    // root row = freeR parity-0 entry (written by k_stepB(93)), composed by k_stepA(94)
    int root = freeR[b];
    if (tid < HH) x0[tid] = state[((size_t)b * RB + root) * DD + HH + tid];
    __syncthreads();
    {
        float a0 = bm1[tid], a1 = bm1[256 + tid], a2 = bm1[512 + tid], a3 = bm1[768 + tid];
        for (int e = 0; e < HH; e++) {
            float x = x0[e];
            a0 += x * Wm1[e * MLPD + tid];
            a1 += x * Wm1[e * MLPD + 256 + tid];
            a2 += x * Wm1[e * MLPD + 512 + tid];
            a3 += x * Wm1[e * MLPD + 768 + tid];
        }
        x1[tid] = fmaxf(a0, 0.f); x1[256 + tid] = fmaxf(a1, 0.f);
        x1[512 + tid] = fmaxf(a2, 0.f); x1[768 + tid] = fmaxf(a3, 0.f);
    }
    __syncthreads();
    {
        float a0 = bm2[tid], a1 = bm2[256 + tid], a2 = bm2[512 + tid], a3 = bm2[768 + tid];
        for (int e = 0; e < MLPD; e++) {
            float x = x1[e];
            a0 += x * Wm2[e * MLPD + tid];
            a1 += x * Wm2[e * MLPD + 256 + tid];
            a2 += x * Wm2[e * MLPD + 512 + tid];
            a3 += x * Wm2[e * MLPD + 768 + tid];
        }
        x2[tid] = fmaxf(a0, 0.f); x2[256 + tid] = fmaxf(a1, 0.f);
        x2[512 + tid] = fmaxf(a2, 0.f); x2[768 + tid] = fmaxf(a3, 0.f);
    }
    __syncthreads();
    {
        float p0 = 0.f, p1 = 0.f, p2 = 0.f;
        for (int e = tid; e < MLPD; e += 256) {
            float x = x2[e];
            p0 += x * Wout[e * NCLS + 0];
            p1 += x * Wout[e * NCLS + 1];
            p2 += x * Wout[e * NCLS + 2];
        }
        red3[0][tid] = p0; red3[1][tid] = p1; red3[2][tid] = p2;
        __syncthreads();
        for (int sdd = 128; sdd >= 1; sdd >>= 1) {
            if (tid < sdd) {
                red3[0][tid] += red3[0][tid + sdd];
                red3[1][tid] += red3[1][tid + sdd];
                red3[2][tid] += red3[2][tid + sdd];
            }
            __syncthreads();
        }
        if (tid < NCLS) out[b * NCLS + tid] = red3[tid][0] + bout[tid];
    }
}

extern "C" void kernel_launch(void* const* d_in, const int* in_sizes, int n_in,
                              void* d_out, int out_size, void* d_ws, size_t ws_size,
                              hipStream_t stream) {
    const int*   sent  = (const int*)d_in[0];
    // d_in[1] = transitions: unused by the reference
    const float* emb   = (const float*)d_in[2];
    const float* Wenc  = (const float*)d_in[3];
    const float* benc  = (const float*)d_in[4];
    const float* Wcomp = (const float*)d_in[5];
    const float* bcomp = (const float*)d_in[6];
    const float* Wsel1 = (const float*)d_in[7];
    const float* bs1   = (const float*)d_in[8];
    const float* Ws2   = (const float*)d_in[9];
    const float* bs2   = (const float*)d_in[10];
    const float* Wm1   = (const float*)d_in[11];
    const float* bm1   = (const float*)d_in[12];
    const float* Wm2   = (const float*)d_in[13];
    const float* bm2   = (const float*)d_in[14];
    const float* Wout  = (const float*)d_in[15];
    const float* bout  = (const float*)d_in[16];
    float* out = (float*)d_out;

    float* ws     = (float*)d_ws;
    float* state  = ws;                              // 64*97*512 = 3,178,496 f32
    float* Wc4    = ws + 3178496;                    // 655,360 f32
    float* Ws14   = ws + 3833856;                    // 65,536 f32
    float* logits = ws + 3899392;                    // 2*64*96 = 12,288 f32 (ping-pong)
    int*   acts   = (int*)(ws + 3911680);            // 2*64*96 ints (ping-pong)
    int*   freeR  = (int*)(ws + 3923968);            // 2*64 ints (ping-pong)

    k_trans_comp<<<dim3(128), dim3(256), 0, stream>>>(Wcomp, Wc4);
    k_trans_sel<<<dim3(128), dim3(128), 0, stream>>>(Wsel1, Ws14);
    k_init<<<dim3(NB), dim3(SS), 0, stream>>>(acts, freeR);
    k_encode<<<dim3(NB * 3), dim3(512), 0, stream>>>(sent, emb, Wenc, benc, state);
    k_logits0<<<dim3(NB * 5), dim3(128), 0, stream>>>(state, Ws14, bs1, Ws2, bs2, logits);

    for (int t = 0; t < SS - 2; t++) {   // t = 0..93
        k_stepA<<<dim3(256), dim3(320), 0, stream>>>(Wc4, bcomp, logits, acts, freeR, state, t);
        k_stepB<<<dim3(128), dim3(256), 0, stream>>>(Ws14, bs1, Ws2, bs2, logits, acts, freeR, state, t);
    }
    k_stepA<<<dim3(256), dim3(320), 0, stream>>>(Wc4, bcomp, logits, acts, freeR, state, SS - 2); // t=94
    k_mlp<<<dim3(NB), dim3(256), 0, stream>>>(state, freeR, Wm1, bm1, Wm2, bm2, Wout, bout, out);
}

// Round 4
// 1478.905 us; speedup vs baseline: 9.4463x; 1.5298x over previous
//
#include <hip/hip_runtime.h>
#include <math.h>

#define NB   64
#define SS   96
#define EE   300
#define DD   512
#define HH   256
#define SELD 128
#define CK   1280   // 5*H
#define MLPD 1024
#define NCLS 3
#define RB   97     // state rows per batch: 96 initial + 1 spare (freed-row recycling)

// ---------------- transpose W_sel1 [e][k] -> [e4][k] float4 (4 consecutive e rows at col k) ------
__global__ void k_trans_sel(const float* __restrict__ Ws, float* __restrict__ Ws4) {
    int e4 = blockIdx.x;            // 0..127
    int k = threadIdx.x;            // 0..127
    float4 v;
    v.x = Ws[(4 * e4 + 0) * SELD + k];
    v.y = Ws[(4 * e4 + 1) * SELD + k];
    v.z = Ws[(4 * e4 + 2) * SELD + k];
    v.w = Ws[(4 * e4 + 3) * SELD + k];
    ((float4*)Ws4)[e4 * SELD + k] = v;
}

// ---------------- init parity-0 bookkeeping ------------------------------------------------------
__global__ void k_init(int* __restrict__ acts, int* __restrict__ rec) {
    int b = blockIdx.x, tid = threadIdx.x;
    acts[b * SS + tid] = tid;                     // parity-0
    if (tid == 0) {
        int* r = rec + b * 4;                     // parity-0
        r[0] = 0; r[1] = 0; r[2] = 0; r[3] = SS;  // pidx, pv0, pv1, freerow
    }
}

// ---------------- encode: states[b][s][:] = emb[sent[b][s]] @ W_enc + b_enc ----------------------
__global__ __launch_bounds__(512) void k_encode(const int* __restrict__ sent,
                                                const float* __restrict__ emb,
                                                const float* __restrict__ Wenc,
                                                const float* __restrict__ benc,
                                                float* __restrict__ state) {
    int b = blockIdx.x / 3, tile = blockIdx.x % 3, s0 = tile * 32;
    __shared__ int tok[32];
    __shared__ __align__(16) float elds[32 * 300];
    int tid = threadIdx.x;
    if (tid < 32) tok[tid] = sent[b * SS + s0 + tid];
    __syncthreads();
    for (int i = tid; i < 32 * 300; i += 512) {
        int s = i / 300, e = i - s * 300;
        elds[i] = emb[(long)tok[s] * EE + e];
    }
    __syncthreads();
    int d = tid;
    float bv = benc[d];
    float acc[32];
#pragma unroll
    for (int s = 0; s < 32; s++) acc[s] = bv;
    for (int e4 = 0; e4 < 75; e4++) {
        float w0 = Wenc[(4 * e4 + 0) * DD + d];
        float w1 = Wenc[(4 * e4 + 1) * DD + d];
        float w2 = Wenc[(4 * e4 + 2) * DD + d];
        float w3 = Wenc[(4 * e4 + 3) * DD + d];
#pragma unroll
        for (int s = 0; s < 32; s++) {
            float4 x = *(const float4*)&elds[s * 300 + 4 * e4];
            acc[s] += x.x * w0 + x.y * w1 + x.z * w2 + x.w * w3;
        }
    }
    for (int s = 0; s < 32; s++)
        state[((size_t)b * RB + s0 + s) * DD + d] = acc[s];
}

// ---------------- initial logits for all 95 pairs per batch (parity-0) ---------------------------
__global__ __launch_bounds__(128) void k_logits0(const float* __restrict__ state,
                                                 const float* __restrict__ Ws4,
                                                 const float* __restrict__ bs1,
                                                 const float* __restrict__ Ws2,
                                                 const float* __restrict__ bs2,
                                                 float* __restrict__ logits) {
    int b = blockIdx.x / 5, tile = blockIdx.x % 5, p0 = tile * 19;
    __shared__ __align__(16) float hl[20 * 256];
    __shared__ float part[2][19];
    int tid = threadIdx.x;
    for (int i = tid; i < 20 * 256; i += 128) {
        int r = i >> 8, c = i & 255;
        hl[i] = state[((size_t)b * RB + p0 + r) * DD + HH + c];
    }
    __syncthreads();
    int k = tid;
    float acc[19];
#pragma unroll
    for (int p = 0; p < 19; p++) acc[p] = 0.f;
    const float4* W4 = (const float4*)Ws4;
    const float4* h4 = (const float4*)hl;
    for (int e4 = 0; e4 < 128; e4++) {
        float4 w = W4[e4 * SELD + k];
#pragma unroll
        for (int p = 0; p < 19; p++) {
            float4 x = h4[p * 64 + e4];
            acc[p] += x.x * w.x + x.y * w.y + x.z * w.z + x.w * w.w;
        }
    }
    float b1 = bs1[k], w2 = Ws2[k];
    int wid = tid >> 6, lane = tid & 63;
#pragma unroll
    for (int p = 0; p < 19; p++) {
        float y = tanhf(acc[p] + b1) * w2;
        for (int off = 32; off >= 1; off >>= 1) y += __shfl_down(y, off);
        if (lane == 0) part[wid][p] = y;
    }
    __syncthreads();
    if (tid < 19) logits[b * SS + p0 + tid] = part[0][tid] + part[1][tid] + bs2[0];
}

// ---------------- fused step kernel: 256 blocks = 16 batch-groups x 16 unit-tiles ----------------
// block (bg, ut): batches bg*4..bg*4+3; h-units U = ut*16..ut*16+15 (all 5 gates).
// Phase 1: finish the 2 refreshed logits from prev step's Psel partials (linear partial-sum trick).
// Phase 2: patch + argmax (redundant per block, per-wave per-batch).
// Phase 3-5: compose matvec for own 80 columns, gates, write c,h of fresh row.
// Phase 6: emit own 32-dim sel partials for next step's 2 refreshed pairs.
// Phase 7 (ut==0): shift bookkeeping into parity t+1.
__global__ __launch_bounds__(320) void k_step(const float* __restrict__ Wc,
                                              const float* __restrict__ bcomp,
                                              const float* __restrict__ Ws4,
                                              const float* __restrict__ bs1,
                                              const float* __restrict__ Ws2,
                                              const float* __restrict__ bs2,
                                              float* __restrict__ logits,
                                              int* __restrict__ acts,
                                              int* __restrict__ rec,
                                              int* __restrict__ nlUsed,
                                              float* __restrict__ Psel,
                                              float* __restrict__ state, int t) {
    int bid = blockIdx.x, bg = bid & 15, ut = bid >> 4;
    int tid = threadIdx.x, w = tid >> 6, lane = tid & 63;
    int n = SS - t, p = t & 1, np = p ^ 1;

    __shared__ float lgl[4][SS];                 // patched logits copies
    __shared__ int recl[4][8];                   // idx,l,r,nl,lm1,r2,v0,v1
    __shared__ float L01[4][2];
    __shared__ __align__(16) float4 xst[4][128]; // [h_l | h_r] per batch
    __shared__ float cl[4][16], cr[4][16];
    __shared__ float lm1s[4][16], r2s[4][16];
    __shared__ float hn[4][16];
    __shared__ float spart[4][80][4];            // [ks][g*16+u][b]
    __shared__ float a_l[4][5][16];
    __shared__ float ppex[4][2][2][SELD];        // [b][pair][whichW][k]

    // ---- phase 1: refresh values for the 2 holes ----
    if (t > 0 && tid < 256) {
        int b = bg * 4 + w;
        const int* rp = rec + ((size_t)p * NB + b) * 4;
        int pv0 = rp[1], pv1 = rp[2];
        if (pv0 | pv1) {
            float sA0 = bs1[lane], sA1 = bs1[lane + 64];
            float sB0 = sA0, sB1 = sA1;
            const float* Pb = Psel + ((size_t)(p * NB + b) * 16) * 256;
#pragma unroll
            for (int u2 = 0; u2 < 16; u2++) {
                const float* Pu = Pb + u2 * 256;
                sA0 += Pu[lane]; sA1 += Pu[lane + 64];
                sB0 += Pu[128 + lane]; sB1 += Pu[128 + lane + 64];
            }
            float yA = tanhf(sA0) * Ws2[lane] + tanhf(sA1) * Ws2[lane + 64];
            float yB = tanhf(sB0) * Ws2[lane] + tanhf(sB1) * Ws2[lane + 64];
#pragma unroll
            for (int off = 1; off < 64; off <<= 1) {
                yA += __shfl_xor(yA, off);
                yB += __shfl_xor(yB, off);
            }
            if (lane == 0) { L01[w][0] = yA + bs2[0]; L01[w][1] = yB + bs2[0]; }
        }
    }
    __syncthreads();

    // ---- phase 2: patch + argmax (numpy first-max) ----
    if (tid < 256) {
        int b = bg * 4 + w;
        const float* lgp = logits + ((size_t)p * NB + b) * SS;
        const int* rp = rec + ((size_t)p * NB + b) * 4;
        int pidx = rp[0], pv0 = rp[1], pv1 = rp[2], freerow = rp[3];
        int j0 = lane, j1 = lane + 64;
        float x0v = (j0 <= n - 2) ? lgp[j0] : -3.0e38f;
        float x1v = (j1 <= n - 2) ? lgp[j1] : -3.0e38f;
        if (t > 0) {
            if (pv0) { if (j0 == pidx - 1) x0v = L01[w][0]; if (j1 == pidx - 1) x1v = L01[w][0]; }
            if (pv1) { if (j0 == pidx)     x0v = L01[w][1]; if (j1 == pidx)     x1v = L01[w][1]; }
        }
        if (j0 <= n - 2) lgl[w][j0] = x0v;
        if (j1 <= n - 2) lgl[w][j1] = x1v;
        float v = x0v; int i = j0;
        if (x1v > v) { v = x1v; i = j1; }
#pragma unroll
        for (int off = 1; off < 64; off <<= 1) {
            float ov = __shfl_xor(v, off);
            int oi = __shfl_xor(i, off);
            if (ov > v || (ov == v && oi < i)) { v = ov; i = oi; }
        }
        if (lane == 0) {
            const int* acp = acts + ((size_t)p * NB + b) * SS;
            int idx = i;
            int l = acp[idx], r = acp[idx + 1];
            int v0 = (idx >= 1), v1 = (idx <= n - 3);
            recl[w][0] = idx; recl[w][1] = l; recl[w][2] = r; recl[w][3] = freerow;
            recl[w][4] = v0 ? acp[idx - 1] : 0;
            recl[w][5] = v1 ? acp[idx + 2] : 0;
            recl[w][6] = v0; recl[w][7] = v1;
        }
    }
    __syncthreads();

    float* st = state + (size_t)(bg * 4) * RB * DD;   // note: per-batch offset added below

    // ---- phase 3: stage x = [h_l | h_r], plus unit slices ----
    for (int i = tid; i < 512; i += 320) {
        int b = i >> 7, j4 = i & 127;
        int row = (j4 < 64) ? recl[b][1] : recl[b][2];
        const float4* src = (const float4*)(state + ((size_t)(bg * 4 + b) * RB + row) * DD + HH);
        xst[b][j4] = src[j4 & 63];
    }
    if (tid < 256) {
        int b = tid >> 6, r6 = tid & 63, which = r6 >> 4, u = r6 & 15;
        const float* sb = state + (size_t)(bg * 4 + b) * RB * DD;
        if (which == 0)      cl[b][u]   = sb[(size_t)recl[b][1] * DD + ut * 16 + u];
        else if (which == 1) cr[b][u]   = sb[(size_t)recl[b][2] * DD + ut * 16 + u];
        else if (which == 2) lm1s[b][u] = sb[(size_t)recl[b][4] * DD + HH + ut * 16 + u];
        else                 r2s[b][u]  = sb[(size_t)recl[b][5] * DD + HH + ut * 16 + u];
    }
    __syncthreads();

    // ---- phase 4: compose matvec, own 80 columns, K-split x4 ----
    {
        int ks = tid / 80, rem = tid % 80, g = rem / 16, u = rem % 16;
        int c = g * 256 + ut * 16 + u;
        float acc0 = 0.f, acc1 = 0.f, acc2 = 0.f, acc3 = 0.f;
        for (int e4 = ks * 32; e4 < ks * 32 + 32; e4++) {
            int e = 4 * e4;
            float w0 = Wc[(size_t)(e + 0) * CK + c];
            float w1 = Wc[(size_t)(e + 1) * CK + c];
            float w2v = Wc[(size_t)(e + 2) * CK + c];
            float w3v = Wc[(size_t)(e + 3) * CK + c];
            float4 xv;
            xv = xst[0][e4]; acc0 += xv.x * w0 + xv.y * w1 + xv.z * w2v + xv.w * w3v;
            xv = xst[1][e4]; acc1 += xv.x * w0 + xv.y * w1 + xv.z * w2v + xv.w * w3v;
            xv = xst[2][e4]; acc2 += xv.x * w0 + xv.y * w1 + xv.z * w2v + xv.w * w3v;
            xv = xst[3][e4]; acc3 += xv.x * w0 + xv.y * w1 + xv.z * w2v + xv.w * w3v;
        }
        spart[ks][rem][0] = acc0; spart[ks][rem][1] = acc1;
        spart[ks][rem][2] = acc2; spart[ks][rem][3] = acc3;
    }
    __syncthreads();
    {
        int b = tid / 80, col = tid % 80;
        int g = col / 16, u = col % 16;
        int c = g * 256 + ut * 16 + u;
        a_l[b][g][u] = spart[0][col][b] + spart[1][col][b] + spart[2][col][b] + spart[3][col][b]
                       + bcomp[c];
    }
    __syncthreads();
    // ---- phase 5: gates + write composed c,h into fresh row ----
    if (tid < 64) {
        int b = tid >> 4, u = tid & 15;
        float ai = a_l[b][0][u], afl = a_l[b][1][u], afr = a_l[b][2][u];
        float ao = a_l[b][3][u], agc = a_l[b][4][u];
        float si  = 1.f / (1.f + expf(-ai));
        float sfl = 1.f / (1.f + expf(-afl));
        float sfr = 1.f / (1.f + expf(-afr));
        float so  = 1.f / (1.f + expf(-ao));
        float cv = sfl * cl[b][u] + sfr * cr[b][u] + si * tanhf(agc);
        float hv = so * tanhf(cv);
        float* sb = state + (size_t)(bg * 4 + b) * RB * DD;
        int nl = recl[b][3];
        sb[(size_t)nl * DD + ut * 16 + u] = cv;
        sb[(size_t)nl * DD + HH + ut * 16 + u] = hv;
        hn[b][u] = hv;
    }
    __syncthreads();

    // ---- phase 6: sel partials for next step (own 32 x-dims) ----
    if (tid < 256) {
        int k = tid & 127, whichW = tid >> 7;
        int e4base = (whichW ? 64 : 0) + ut * 4;
        const float4* W4 = (const float4*)Ws4;
        float P0[4] = {0.f, 0.f, 0.f, 0.f}, P1[4] = {0.f, 0.f, 0.f, 0.f};
#pragma unroll
        for (int j = 0; j < 4; j++) {
            float4 wv = W4[(size_t)(e4base + j) * SELD + k];
#pragma unroll
            for (int b4 = 0; b4 < 4; b4++) {
                const float* xa0 = whichW ? hn[b4] : lm1s[b4];
                const float* xa1 = whichW ? r2s[b4] : hn[b4];
                P0[b4] += wv.x * xa0[4 * j] + wv.y * xa0[4 * j + 1]
                        + wv.z * xa0[4 * j + 2] + wv.w * xa0[4 * j + 3];
                P1[b4] += wv.x * xa1[4 * j] + wv.y * xa1[4 * j + 1]
                        + wv.z * xa1[4 * j + 2] + wv.w * xa1[4 * j + 3];
            }
        }
#pragma unroll
        for (int b4 = 0; b4 < 4; b4++) {
            ppex[b4][0][whichW][k] = P0[b4];
            ppex[b4][1][whichW][k] = P1[b4];
        }
    }
    __syncthreads();
    if (tid < 256) {
        int k = tid & 127, pr = tid >> 7;
#pragma unroll
        for (int b4 = 0; b4 < 4; b4++) {
            int b = bg * 4 + b4;
            Psel[((size_t)(np * NB + b) * 16 + ut) * 256 + pr * 128 + k] =
                ppex[b4][pr][0][k] + ppex[b4][pr][1][k];
        }
    }

    // ---- phase 7 (ut==0): shift bookkeeping into parity t+1 ----
    if (ut == 0 && tid < 256) {
        int b = bg * 4 + w;
        int idx = recl[w][0], l = recl[w][1], nl = recl[w][3];
        int v0 = recl[w][6], v1 = recl[w][7];
        const int* acp = acts + ((size_t)p * NB + b) * SS;
        int* acn = acts + ((size_t)np * NB + b) * SS;
        float* lgn = logits + ((size_t)np * NB + b) * SS;
        for (int j = lane; j <= n - 2; j += 64)
            acn[j] = (j < idx) ? acp[j] : ((j == idx) ? nl : acp[j + 1]);
        for (int j = lane; j <= n - 3; j += 64)
            if (j != idx - 1 && j != idx)
                lgn[j] = (j < idx - 1) ? lgl[w][j] : lgl[w][j + 1];
        if (lane == 0) {
            int* rn = rec + ((size_t)np * NB + b) * 4;
            rn[0] = idx; rn[1] = v0; rn[2] = v1; rn[3] = l;
            nlUsed[b] = nl;
        }
    }
}

// ---------------- MLP head, column-parallel ------------------------------------------------------
__global__ __launch_bounds__(256) void k_mlp1(const float* __restrict__ state,
                                              const int* __restrict__ nlUsed,
                                              const float* __restrict__ Wm1,
                                              const float* __restrict__ bm1,
                                              float* __restrict__ x1g) {
    int b = blockIdx.x >> 2, q = blockIdx.x & 3, tid = threadIdx.x;
    int col = q * 256 + tid;
    __shared__ float x0[HH];
    int root = nlUsed[b];
    x0[tid] = state[((size_t)b * RB + root) * DD + HH + tid];
    __syncthreads();
    float acc = bm1[col];
    for (int e = 0; e < HH; e++) acc += x0[e] * Wm1[(size_t)e * MLPD + col];
    x1g[(size_t)b * MLPD + col] = fmaxf(acc, 0.f);
}

__global__ __launch_bounds__(128) void k_mlp2(const float* __restrict__ x1g,
                                              const float* __restrict__ Wm2,
                                              const float* __restrict__ bm2,
                                              float* __restrict__ x2g) {
    int b = blockIdx.x >> 3, q = blockIdx.x & 7, tid = threadIdx.x;
    int col = q * 128 + tid;
    __shared__ __align__(16) float x1[MLPD];
    for (int i = tid; i < 256; i += 128)
        ((float4*)x1)[i] = ((const float4*)(x1g + (size_t)b * MLPD))[i];
    __syncthreads();
    float acc = bm2[col];
    for (int e = 0; e < MLPD; e++) acc += x1[e] * Wm2[(size_t)e * MLPD + col];
    x2g[(size_t)b * MLPD + col] = fmaxf(acc, 0.f);
}

__global__ __launch_bounds__(256) void k_mlp3(const float* __restrict__ x2g,
                                              const float* __restrict__ Wout,
                                              const float* __restrict__ bout,
                                              float* __restrict__ out) {
    int b = blockIdx.x, tid = threadIdx.x;
    __shared__ __align__(16) float x2[MLPD];
    __shared__ float red3[3][256];
    ((float4*)x2)[tid] = ((const float4*)(x2g + (size_t)b * MLPD))[tid];
    __syncthreads();
    float p0 = 0.f, p1 = 0.f, p2 = 0.f;
    for (int e = tid; e < MLPD; e += 256) {
        float x = x2[e];
        p0 += x * Wout[e * NCLS + 0];
        p1 += x * Wout[e * NCLS + 1];
        p2 += x * Wout[e * NCLS + 2];
    }
    red3[0][tid] = p0; red3[1][tid] = p1; red3[2][tid] = p2;
    __syncthreads();
    for (int sdd = 128; sdd >= 1; sdd >>= 1) {
        if (tid < sdd) {
            red3[0][tid] += red3[0][tid + sdd];
            red3[1][tid] += red3[1][tid + sdd];
            red3[2][tid] += red3[2][tid + sdd];
        }
        __syncthreads();
    }
    if (tid < NCLS) out[b * NCLS + tid] = red3[tid][0] + bout[tid];
}

extern "C" void kernel_launch(void* const* d_in, const int* in_sizes, int n_in,
                              void* d_out, int out_size, void* d_ws, size_t ws_size,
                              hipStream_t stream) {
    const int*   sent  = (const int*)d_in[0];
    // d_in[1] = transitions: unused by the reference
    const float* emb   = (const float*)d_in[2];
    const float* Wenc  = (const float*)d_in[3];
    const float* benc  = (const float*)d_in[4];
    const float* Wcomp = (const float*)d_in[5];
    const float* bcomp = (const float*)d_in[6];
    const float* Wsel1 = (const float*)d_in[7];
    const float* bs1   = (const float*)d_in[8];
    const float* Ws2   = (const float*)d_in[9];
    const float* bs2   = (const float*)d_in[10];
    const float* Wm1   = (const float*)d_in[11];
    const float* bm1   = (const float*)d_in[12];
    const float* Wm2   = (const float*)d_in[13];
    const float* bm2   = (const float*)d_in[14];
    const float* Wout  = (const float*)d_in[15];
    const float* bout  = (const float*)d_in[16];
    float* out = (float*)d_out;

    float* ws     = (float*)d_ws;
    float* state  = ws;                              // 3,178,496 f32
    float* Ws14   = ws + 3178496;                    // 65,536
    float* logits = ws + 3244032;                    // 2*64*96 = 12,288 (ping-pong)
    int*   acts   = (int*)(ws + 3256320);            // 12,288 ints (ping-pong)
    int*   rec    = (int*)(ws + 3268608);            // 512 ints (ping-pong)
    int*   nlUsed = (int*)(ws + 3269120);            // 64 ints
    float* Psel   = ws + 3269184;                    // 2*64*16*256 = 524,288 (ping-pong)
    float* x1g    = ws + 3269184;                    // alias: Psel dead after scan
    float* x2g    = ws + 3334720;                    // alias

    k_trans_sel<<<dim3(128), dim3(128), 0, stream>>>(Wsel1, Ws14);
    k_init<<<dim3(NB), dim3(SS), 0, stream>>>(acts, rec);
    k_encode<<<dim3(NB * 3), dim3(512), 0, stream>>>(sent, emb, Wenc, benc, state);
    k_logits0<<<dim3(NB * 5), dim3(128), 0, stream>>>(state, Ws14, bs1, Ws2, bs2, logits);

    for (int t = 0; t < SS - 1; t++)   // t = 0..94
        k_step<<<dim3(256), dim3(320), 0, stream>>>(Wcomp, bcomp, Ws14, bs1, Ws2, bs2,
                                                    logits, acts, rec, nlUsed, Psel, state, t);

    k_mlp1<<<dim3(NB * 4), dim3(256), 0, stream>>>(state, nlUsed, Wm1, bm1, x1g);
    k_mlp2<<<dim3(NB * 8), dim3(128), 0, stream>>>(x1g, Wm2, bm2, x2g);
    k_mlp3<<<dim3(NB), dim3(256), 0, stream>>>(x2g, Wout, bout, out);
}